// Round 8
// baseline (152.576 us; speedup 1.0000x reference)
//
#include <hip/hip_runtime.h>
#include <hip/hip_bf16.h>

#define HWP 9216   // H*W
#define HH  96
#define WW  96
#define CC  256    // Cin == Cout
#define NB  2

typedef __attribute__((ext_vector_type(8))) short bf16x8;
typedef __attribute__((ext_vector_type(4))) float f32x4;

__device__ inline unsigned short f2bf(float f) {
  union { __hip_bfloat16 h; unsigned short u; } cvt;
  cvt.h = __float2bfloat16(f);
  return cvt.u;
}
__device__ inline float bf_lo(unsigned int u) { return __uint_as_float(u << 16); }
__device__ inline float bf_hi(unsigned int u) { return __uint_as_float(u & 0xffff0000u); }

// ====================== R17 ======================
// MEASURED: fills ~88us FIXED; k_gather ~16us (near its 340MB-L2 floor after
// R15 occupancy + R16 uint4 load-halving); k_main ~13us at only 2.25 blocks/CU
// with a serial offs-MFMA tail.
// R17: (a) k_main BN=128 split -> grid 1152, LDS 25.6KB, ~4.5 blocks/CU;
// epilogue = xpb write only. x nontemporal hint dropped (2 readers now;
// strip is L2/L3-resident). (b) offs computed inside k_gather phase 0o
// (144 threads x 256-dot from xpb bf16 rows x off_w f32 + off_b -> LDS);
// offs workspace eliminated. Offs numerics: same bf16 xp, f32 accum,
// different order -> ~1e-3 offset deltas on a continuous bilinear map
// (margin 0.031 vs 0.105 threshold).
// PITFALL (R12): cooperative grid.sync under graph capture silently broken
// — never fuse across the xpb producer/consumer boundary.
// Pitfalls kept: MFMA-frag register-prefetch (R6/R7) REGRESSED; BK=64 (R9)
// REGRESSED; keep BK=32, pad-40 LDS (2-way = free).

__global__ __launch_bounds__(256) void k_main(const float* __restrict__ x,
                                              const float* __restrict__ pw_w,
                                              unsigned short* __restrict__ xpb) {
  __shared__ unsigned short As[2][32 * 40];    // [pix][k] dbuf
  __shared__ unsigned short Bs[2][128 * 40];   // [n][k] dbuf; Bs[0] reused as Cs

  // XCD-aligned decode: g -> (e, nh, b, m); both ch-halves of a strip share e
  int g    = blockIdx.x;         // 0..1151
  int e    = g & 7;
  int idx  = g >> 3;             // 0..143
  int nh   = idx & 1;            // channel half
  int idx2 = idx >> 1;           // 0..71
  int b    = idx2 / 36;
  int m    = idx2 - b * 36;      // 0..35
  int pix0 = (e * 36 + m) * 32;  // local pixel within batch
  int nb0  = nh * 128;           // output-channel base

  int t    = threadIdx.x;
  int lane = t & 63;
  int w    = t >> 6;
  int mw  = (w & 1) * 16;        // wave pixel tile
  int nwl = (w >> 1) * 64;       // wave channel quarter (of 128)
  int r = lane & 15, q = lane >> 4;

  f32x4 acc[4] = {};

  const float* xg = x + (size_t)b * CC * HWP + pix0;
  int sc = t >> 3;           // channel within 32-chunk
  int sp = (t & 7) * 4;      // pixel offset
  int nB = t >> 1;           // B row (0..127)
  int kh = (t & 1) * 16;     // B k-offset

  // ---- prologue: stage K-step 0 into buf 0 (B converted inline from f32)
  {
    f32x4 xv = *(const f32x4*)(xg + (size_t)sc * HWP + sp);
    As[0][(sp + 0) * 40 + sc] = f2bf(xv.x);
    As[0][(sp + 1) * 40 + sc] = f2bf(xv.y);
    As[0][(sp + 2) * 40 + sc] = f2bf(xv.z);
    As[0][(sp + 3) * 40 + sc] = f2bf(xv.w);
    const float* wp = pw_w + (size_t)(nb0 + nB) * 256 + kh;
#pragma unroll
    for (int h = 0; h < 2; ++h) {
      float4 w0 = *(const float4*)(wp + h * 8);
      float4 w1 = *(const float4*)(wp + h * 8 + 4);
      union { ushort4 s[2]; uint4 q4; } pk;
      pk.s[0] = make_ushort4(f2bf(w0.x), f2bf(w0.y), f2bf(w0.z), f2bf(w0.w));
      pk.s[1] = make_ushort4(f2bf(w1.x), f2bf(w1.y), f2bf(w1.z), f2bf(w1.w));
      *(uint4*)&Bs[0][nB * 40 + kh + h * 8] = pk.q4;
    }
  }
  __syncthreads();

  // ---- main loop: 1 barrier per K-step, prefetch t+1 overlapped with MFMA(t)
  for (int kt = 0; kt < 8; ++kt) {
    int cur = kt & 1;
    f32x4 xv;
    float4 b0[2], b1[2];
    bool pre = (kt < 7);
    if (pre) {
      int k0 = (kt + 1) * 32;
      xv = *(const f32x4*)(xg + (size_t)(k0 + sc) * HWP + sp);
      const float* wp = pw_w + (size_t)(nb0 + nB) * 256 + k0 + kh;
#pragma unroll
      for (int h = 0; h < 2; ++h) {
        b0[h] = *(const float4*)(wp + h * 8);
        b1[h] = *(const float4*)(wp + h * 8 + 4);
      }
    }
    bf16x8 a = *(const bf16x8*)&As[cur][(mw + r) * 40 + q * 8];
#pragma unroll
    for (int nt = 0; nt < 4; ++nt) {
      bf16x8 bb = *(const bf16x8*)&Bs[cur][(nwl + nt * 16 + r) * 40 + q * 8];
      acc[nt] = __builtin_amdgcn_mfma_f32_16x16x32_bf16(a, bb, acc[nt], 0, 0, 0);
    }
    if (pre) {
      int nx = cur ^ 1;
      As[nx][(sp + 0) * 40 + sc] = f2bf(xv.x);
      As[nx][(sp + 1) * 40 + sc] = f2bf(xv.y);
      As[nx][(sp + 2) * 40 + sc] = f2bf(xv.z);
      As[nx][(sp + 3) * 40 + sc] = f2bf(xv.w);
#pragma unroll
      for (int h = 0; h < 2; ++h) {
        union { ushort4 s[2]; uint4 q4; } pk;
        pk.s[0] = make_ushort4(f2bf(b0[h].x), f2bf(b0[h].y), f2bf(b0[h].z), f2bf(b0[h].w));
        pk.s[1] = make_ushort4(f2bf(b1[h].x), f2bf(b1[h].y), f2bf(b1[h].z), f2bf(b1[h].w));
        *(uint4*)&Bs[nx][nB * 40 + kh + h * 8] = pk.q4;
      }
    }
    __syncthreads();
  }

  // Cs aliases Bs[0]: last K-step read buf 1; final sync drained buf 0 reads.
  unsigned short* Cs = &Bs[0][0];   // [32][136] bf16 (4352 shorts <= 5120)

  // C/D: col = lane&15 (ch), row = q*4+rr (pix) -> Cs[pix][ch] bf16
#pragma unroll
  for (int nt = 0; nt < 4; ++nt)
#pragma unroll
    for (int rr = 0; rr < 4; ++rr)
      Cs[(mw + q * 4 + rr) * 136 + nwl + nt * 16 + r] = f2bf(acc[nt][rr]);
  __syncthreads();

  // write xpb coalesced: 32 B contiguous per thread (128-ch half)
  {
    int pix = t >> 3, c16 = (t & 7) * 16;
    unsigned short* o = xpb + ((size_t)b * HWP + pix0 + pix) * CC + nb0 + c16;
    *(uint4*)(o + 0) = *(const uint4*)&Cs[pix * 136 + c16 + 0];
    *(uint4*)(o + 8) = *(const uint4*)&Cs[pix * 136 + c16 + 8];
  }
}

// ---- gather + depthwise: 8 px/block, half-wave pixel split (R16), plus
// R17 phase 0o: offs computed in-block from xpb (144 threads, one
// (pixel, o) 256-dot each; off_w kept f32 — continuous bilinear tolerates
// ~1e-3 offset deltas).
// Hard-won pitfalls:
//  * NO launch-bounds min-wave arg (R6: forced VGPR 64 -> scratch spills, 3x)
//  * NO nontemporal output stores (R4: 4x WRITE_SIZE amplification)
__global__ __launch_bounds__(256) void k_gather(const unsigned short* __restrict__ xp,
                                                const float* __restrict__ off_w,
                                                const float* __restrict__ off_b,
                                                const float* __restrict__ dw_w,
                                                float* __restrict__ out) {
  __shared__ float Cs[8][257];
  __shared__ float4 Wt[8][9];    // bilinear weights per (pixel, tap)
  __shared__ int4   Ad[8][9];    // corner row byte-offsets per (pixel, tap)
  __shared__ float  dvs[9][257]; // dw_w transposed [tap][ch]
  __shared__ float  offv[8][20]; // computed offsets per (pixel, 2*tap)

  // XCD-aligned decode: g -> (e, b, m2); chunk c = e*144 + m2 (8 px each)
  int g   = blockIdx.x;          // 0..2303
  int e   = g & 7;
  int idx = g >> 3;              // 0..287
  int b   = idx / 144;
  int m2  = idx - b * 144;       // 0..143
  int c   = e * 144 + m2;        // 0..1151
  int hw0 = c * 8;               // pixel within batch
  int pix0 = b * HWP + hw0;      // global pixel
  (void)pix0;

  int wave = threadIdx.x >> 6;
  int lane = threadIdx.x & 63;
  int hp   = lane >> 5;          // half-wave pixel select (0/1)
  int hl   = lane & 31;          // lane within half-wave
  int ip   = wave * 2 + hp;      // this lane's pixel 0..7
  int c0   = hl * 8;             // this lane's 8-channel base

  const unsigned short* xb = xp + (size_t)b * HWP * CC;

  // ---- phase 0a: stage dw_w transposed (9 scalar loads/thread)
  {
    int t = threadIdx.x;
#pragma unroll
    for (int kk = 0; kk < 9; ++kk)
      dvs[kk][t] = dw_w[t * 9 + kk];
  }

  // ---- phase 0o: compute offs for our 8 pixels from xpb rows (bf16) x
  // off_w (f32): 144 threads, one (pixel, o) dot of length 256 each.
  {
    int tp = threadIdx.x;
    if (tp < 144) {
      int ipp = tp / 18;             // pixel 0..7
      int o   = tp - ipp * 18;       // offset-channel 0..17
      const unsigned short* xrow = xb + (size_t)(hw0 + ipp) * CC;
      const float* wr = off_w + o * 256;
      float a = 0.f;
#pragma unroll 8
      for (int ks = 0; ks < 32; ++ks) {
        uint4 u = *(const uint4*)(xrow + ks * 8);
        float4 w0 = *(const float4*)(wr + ks * 8);
        float4 w1 = *(const float4*)(wr + ks * 8 + 4);
        a += bf_lo(u.x) * w0.x + bf_hi(u.x) * w0.y +
             bf_lo(u.y) * w0.z + bf_hi(u.y) * w0.w +
             bf_lo(u.z) * w1.x + bf_hi(u.z) * w1.y +
             bf_lo(u.w) * w1.z + bf_hi(u.w) * w1.w;
      }
      offv[ipp][o] = a + off_b[o];
    }
  }
  __syncthreads();

  // ---- phase 0b: 72 threads compute the wave-uniform per-(pixel,tap) data
  {
    int tp = threadIdx.x;
    if (tp < 72) {
      int ipp = tp / 9;              // pixel 0..7
      int kk = tp - ipp * 9;         // tap 0..8
      int hw = hw0 + ipp;
      int h = hw / WW;
      int wq = hw - h * WW;
      float y = (float)(h + kk / 3 - 1) + offv[ipp][2 * kk];
      float x = (float)(wq + kk % 3 - 1) + offv[ipp][2 * kk + 1];
      float y0f = floorf(y), x0f = floorf(x);
      float fy = y - y0f, fx = x - x0f;
      int y0 = (int)y0f, x0 = (int)x0f;
      int y1 = y0 + 1, x1 = x0 + 1;
      bool vy0 = (y0 >= 0) & (y0 < HH);
      bool vy1 = (y1 >= 0) & (y1 < HH);
      bool vx0 = (x0 >= 0) & (x0 < WW);
      bool vx1 = (x1 >= 0) & (x1 < WW);
      int y0c = y0 < 0 ? 0 : (y0 > HH - 1 ? HH - 1 : y0);
      int y1c = y1 < 0 ? 0 : (y1 > HH - 1 ? HH - 1 : y1);
      int x0c = x0 < 0 ? 0 : (x0 > WW - 1 ? WW - 1 : x0);
      int x1c = x1 < 0 ? 0 : (x1 > WW - 1 ? WW - 1 : x1);
      Wt[ipp][kk] = make_float4(
          (1.f - fy) * (1.f - fx) * ((vy0 && vx0) ? 1.f : 0.f),
          (1.f - fy) * fx         * ((vy0 && vx1) ? 1.f : 0.f),
          fy * (1.f - fx)         * ((vy1 && vx0) ? 1.f : 0.f),
          fy * fx                 * ((vy1 && vx1) ? 1.f : 0.f));
      Ad[ipp][kk] = make_int4((y0c * WW + x0c) * (CC * 2), (y0c * WW + x1c) * (CC * 2),
                              (y1c * WW + x0c) * (CC * 2), (y1c * WW + x1c) * (CC * 2));
    }
  }
  __syncthreads();

  // ---- main loop: 4 uint4 corner loads per tap; unpack + FMA only.
  const char* xbc = (const char*)xb;
  unsigned lb = (unsigned)(hl * 16);   // this lane's 8-channel byte offset

  float acc[8] = {};
#pragma unroll
  for (int kk = 0; kk < 9; ++kk) {
    float4 dv0 = *(const float4*)&dvs[kk][c0];
    float4 dv1 = *(const float4*)&dvs[kk][c0 + 4];
    float4 wv = Wt[ip][kk];
    int4 av = Ad[ip][kk];
    uint4 u00 = *(const uint4*)(xbc + ((unsigned)av.x + lb));
    uint4 u01 = *(const uint4*)(xbc + ((unsigned)av.y + lb));
    uint4 u10 = *(const uint4*)(xbc + ((unsigned)av.z + lb));
    uint4 u11 = *(const uint4*)(xbc + ((unsigned)av.w + lb));
    const unsigned* p00 = (const unsigned*)&u00;
    const unsigned* p01 = (const unsigned*)&u01;
    const unsigned* p10 = (const unsigned*)&u10;
    const unsigned* p11 = (const unsigned*)&u11;
    float dvv[8] = {dv0.x, dv0.y, dv0.z, dv0.w, dv1.x, dv1.y, dv1.z, dv1.w};
#pragma unroll
    for (int j = 0; j < 4; ++j) {
      unsigned w00 = p00[j], w01 = p01[j], w10 = p10[j], w11 = p11[j];
      float slo = wv.x * bf_lo(w00) + wv.y * bf_lo(w01) + wv.z * bf_lo(w10) + wv.w * bf_lo(w11);
      float shi = wv.x * bf_hi(w00) + wv.y * bf_hi(w01) + wv.z * bf_hi(w10) + wv.w * bf_hi(w11);
      acc[2 * j]     += dvv[2 * j]     * slo;
      acc[2 * j + 1] += dvv[2 * j + 1] * shi;
    }
  }
  *(float4*)&Cs[ip][c0]     = make_float4(acc[0], acc[1], acc[2], acc[3]);
  *(float4*)&Cs[ip][c0 + 4] = make_float4(acc[4], acc[5], acc[6], acc[7]);
  __syncthreads();
  // write-out: thread t = channel, 8 consecutive pixels = 32 B contiguous.
  int ch = threadIdx.x;
  float* ob = out + (size_t)b * CC * HWP + (size_t)ch * HWP + hw0;
  *(float4*)(ob + 0) = make_float4(Cs[0][ch], Cs[1][ch], Cs[2][ch], Cs[3][ch]);
  *(float4*)(ob + 4) = make_float4(Cs[4][ch], Cs[5][ch], Cs[6][ch], Cs[7][ch]);
}

extern "C" void kernel_launch(void* const* d_in, const int* in_sizes, int n_in,
                              void* d_out, int out_size, void* d_ws, size_t ws_size,
                              hipStream_t stream) {
  (void)in_sizes; (void)n_in; (void)out_size; (void)ws_size;
  const float* x     = (const float*)d_in[0];
  const float* pw_w  = (const float*)d_in[1];
  const float* off_w = (const float*)d_in[2];
  const float* off_b = (const float*)d_in[3];
  const float* dw_w  = (const float*)d_in[4];
  float* out = (float*)d_out;

  char* ws = (char*)d_ws;
  unsigned short* xpb = (unsigned short*)ws;            // B*HW*C bf16 = 9,437,184 B

  k_main  <<<1152, 256, 0, stream>>>(x, pw_w, xpb);
  k_gather<<<2304, 256, 0, stream>>>(xpb, off_w, off_b, dw_w, out);
}

// Round 9
// 116.022 us; speedup vs baseline: 1.3151x; 1.3151x over previous
//
#include <hip/hip_runtime.h>
#include <hip/hip_bf16.h>

#define HWP 9216   // H*W
#define HH  96
#define WW  96
#define CC  256    // Cin == Cout
#define NB  2

typedef __attribute__((ext_vector_type(8))) short bf16x8;
typedef __attribute__((ext_vector_type(4))) float f32x4;

__device__ inline unsigned short f2bf(float f) {
  union { __hip_bfloat16 h; unsigned short u; } cvt;
  cvt.h = __float2bfloat16(f);
  return cvt.u;
}
__device__ inline float bf_lo(unsigned int u) { return __uint_as_float(u << 16); }
__device__ inline float bf_hi(unsigned int u) { return __uint_as_float(u & 0xffff0000u); }
// LDS anti-bank-conflict padding: +4 floats every 64. Lane hl's float4 at
// c0=hl*8 then maps to bank-quad (8hl+4*(hl/8))%32 -> 2-way (free, m136),
// and stays 16B-aligned (both terms multiple of 4 dwords).
__device__ inline int padc(int c) { return c + ((c >> 6) << 2); }

// ====================== R18 ======================
// R17 POST-MORTEM (regressed 116.9 -> 152.6): moving offs into k_gather as
// per-block 256-deep scalar dots cost +40us (serial chain + 96 extra loads
// per thread, gating all later phases). PITFALL: never replace a shared MFMA
// product with per-block redundant scalar recompute. But it made k_gather
// visible: 74.2us, bank conflicts 6.3M cy (~10us/CU of LDS serialization),
// FETCH 6.7MB (xpb L2-resident). Revised budget: fills/overhead ~70us FIXED,
// k_main ~13us, k_gather ~33us at R16 (vs ~10us L2-traffic floor).
// R18 = R16 reverted + LDS bank-conflict fix ONLY: dvs/Cs accesses at
// c0=hl*8 floats were 8-way conflicted (32 lanes, stride-32B b128);
// padc() padding makes them 2-way (free). Math bit-identical.
// PITFALL (R12): cooperative grid.sync under graph capture silently broken
// — never fuse across the xpb producer/consumer boundary.

// ---- fused: xp = pw_w . x  (bf16 MFMA, 32 pix x 256 ch per block, BK=32)
//            + offs = off_w . xp + off_b  (MFMA epilogue on the Cs tile)
// 2-phase dbuf (R11). XCD-aligned: block g -> class e=g%8 produces pixel
// strip [e*1152,(e+1)*1152) per batch; k_gather decode matches.
// Pitfalls kept: MFMA-frag register-prefetch (R6/R7) REGRESSED; BK=64 (R9)
// REGRESSED. Keep BK=32, pad-40 layout (2-way = free).
__global__ __launch_bounds__(256) void k_main(const float* __restrict__ x,
                                              const float* __restrict__ pw_w,
                                              const float* __restrict__ off_w,
                                              const float* __restrict__ off_b,
                                              unsigned short* __restrict__ xpb,
                                              float* __restrict__ offs) {
  __shared__ unsigned short As[2][32 * 40];    // [pix][k] dbuf
  __shared__ unsigned short Bs[2][256 * 40];   // [n][k] dbuf; Bs[0] reused as Cs

  int g   = blockIdx.x;          // 0..575
  int e   = g & 7;
  int idx = g >> 3;              // 0..71
  int b   = idx / 36;
  int m   = idx - b * 36;        // 0..35
  int pix0 = (e * 36 + m) * 32;  // local pixel within batch

  int t    = threadIdx.x;
  int lane = t & 63;
  int w    = t >> 6;
  int mw = (w & 1) * 16;     // wave pixel tile
  int nw = (w >> 1) * 128;   // wave channel half
  int r = lane & 15, q = lane >> 4;

  f32x4 acc[8] = {};

  const float* xg = x + (size_t)b * CC * HWP + pix0;
  int sc = t >> 3;           // channel within 32-chunk
  int sp = (t & 7) * 4;      // pixel offset
  int nB = t >> 2;           // B row within 64-group
  int c8 = (t & 3) * 8;      // B k-offset

  // ---- prologue: stage K-step 0 into buf 0 (B converted inline from f32)
  {
    f32x4 xv = __builtin_nontemporal_load((const f32x4*)(xg + (size_t)sc * HWP + sp));
    As[0][(sp + 0) * 40 + sc] = f2bf(xv.x);
    As[0][(sp + 1) * 40 + sc] = f2bf(xv.y);
    As[0][(sp + 2) * 40 + sc] = f2bf(xv.z);
    As[0][(sp + 3) * 40 + sc] = f2bf(xv.w);
#pragma unroll
    for (int rep = 0; rep < 4; ++rep) {
      int n = rep * 64 + nB;
      const float* wp = pw_w + n * 256 + c8;
      float4 w0 = *(const float4*)wp;
      float4 w1 = *(const float4*)(wp + 4);
      union { ushort4 h[2]; uint4 q4; } pk;
      pk.h[0] = make_ushort4(f2bf(w0.x), f2bf(w0.y), f2bf(w0.z), f2bf(w0.w));
      pk.h[1] = make_ushort4(f2bf(w1.x), f2bf(w1.y), f2bf(w1.z), f2bf(w1.w));
      *(uint4*)&Bs[0][n * 40 + c8] = pk.q4;
    }
  }
  __syncthreads();

  // ---- main loop: 1 barrier per K-step, prefetch t+1 overlapped with MFMA(t)
  for (int kt = 0; kt < 8; ++kt) {
    int cur = kt & 1;
    f32x4 xv;
    float4 b0[4], b1[4];
    bool pre = (kt < 7);
    if (pre) {
      int k0 = (kt + 1) * 32;
      xv = __builtin_nontemporal_load((const f32x4*)(xg + (size_t)(k0 + sc) * HWP + sp));
#pragma unroll
      for (int rep = 0; rep < 4; ++rep) {
        const float* wp = pw_w + (rep * 64 + nB) * 256 + k0 + c8;
        b0[rep] = *(const float4*)wp;
        b1[rep] = *(const float4*)(wp + 4);
      }
    }
    bf16x8 a = *(const bf16x8*)&As[cur][(mw + r) * 40 + q * 8];
#pragma unroll
    for (int nt = 0; nt < 8; ++nt) {
      bf16x8 bb = *(const bf16x8*)&Bs[cur][(nw + nt * 16 + r) * 40 + q * 8];
      acc[nt] = __builtin_amdgcn_mfma_f32_16x16x32_bf16(a, bb, acc[nt], 0, 0, 0);
    }
    if (pre) {
      int nx = cur ^ 1;
      As[nx][(sp + 0) * 40 + sc] = f2bf(xv.x);
      As[nx][(sp + 1) * 40 + sc] = f2bf(xv.y);
      As[nx][(sp + 2) * 40 + sc] = f2bf(xv.z);
      As[nx][(sp + 3) * 40 + sc] = f2bf(xv.w);
#pragma unroll
      for (int rep = 0; rep < 4; ++rep) {
        int n = rep * 64 + nB;
        union { ushort4 h[2]; uint4 q4; } pk;
        pk.h[0] = make_ushort4(f2bf(b0[rep].x), f2bf(b0[rep].y), f2bf(b0[rep].z), f2bf(b0[rep].w));
        pk.h[1] = make_ushort4(f2bf(b1[rep].x), f2bf(b1[rep].y), f2bf(b1[rep].z), f2bf(b1[rep].w));
        *(uint4*)&Bs[nx][n * 40 + c8] = pk.q4;
      }
    }
    __syncthreads();
  }

  // Cs aliases Bs[0]: last K-step read buf 1; final sync drained buf 0 reads.
  unsigned short* Cs = &Bs[0][0];   // [pix][ch] bf16, pad 264

  // C/D: col = lane&15 (ch), row = q*4+rr (pix) -> Cs[pix][ch] bf16
#pragma unroll
  for (int nt = 0; nt < 8; ++nt)
#pragma unroll
    for (int rr = 0; rr < 4; ++rr)
      Cs[(mw + q * 4 + rr) * 264 + nw + nt * 16 + r] = f2bf(acc[nt][rr]);
  __syncthreads();

  // write xpb coalesced: 64 B contiguous per thread
  {
    int pix = t >> 3, c32 = (t & 7) * 32;
    unsigned short* o = xpb + ((size_t)b * HWP + pix0 + pix) * CC + c32;
#pragma unroll
    for (int j = 0; j < 4; ++j)
      *(uint4*)(o + j * 8) = *(const uint4*)&Cs[pix * 264 + c32 + j * 8];
  }

  // offset epilogue: offs[pix, o] = sum_c Cs[pix][c] * off_w[o][c] + off_b[o]
  {
    int mw2 = (w & 1) * 16;    // pixel tile
    int nw2 = (w >> 1) * 16;   // o tile (0 or 16)
    int row = nw2 + r;
    f32x4 oacc = {};
#pragma unroll
    for (int ks = 0; ks < CC; ks += 32) {
      bf16x8 a = *(const bf16x8*)&Cs[(mw2 + r) * 264 + ks + q * 8];
      bf16x8 bb = {};
      if (row < 18) {
        const float* wp = off_w + row * 256 + ks + q * 8;
        float4 w0 = *(const float4*)wp;
        float4 w1 = *(const float4*)(wp + 4);
        union { unsigned short u[8]; bf16x8 v; } pk;
        pk.u[0] = f2bf(w0.x); pk.u[1] = f2bf(w0.y); pk.u[2] = f2bf(w0.z); pk.u[3] = f2bf(w0.w);
        pk.u[4] = f2bf(w1.x); pk.u[5] = f2bf(w1.y); pk.u[6] = f2bf(w1.z); pk.u[7] = f2bf(w1.w);
        bb = pk.v;
      }
      oacc = __builtin_amdgcn_mfma_f32_16x16x32_bf16(a, bb, oacc, 0, 0, 0);
    }
    if (row < 18) {
      float ob = off_b[row];
      size_t base = ((size_t)b * HWP + pix0 + mw2 + q * 4) * 20 + row;
#pragma unroll
      for (int rr = 0; rr < 4; ++rr)
        offs[base + (size_t)rr * 20] = oacc[rr] + ob;
    }
  }
}

// ---- gather + depthwise: R16 structure (8 px/block, half-wave pixel split,
// uint4 corner loads) + R18 padc() on dvs/Cs (8-way -> 2-way LDS conflicts).
// Hard-won pitfalls:
//  * NO launch-bounds min-wave arg (R6: forced VGPR 64 -> scratch spills, 3x)
//  * NO nontemporal output stores (R4: 4x WRITE_SIZE amplification)
//  * NO per-block offs recompute (R17: +40us)
__global__ __launch_bounds__(256) void k_gather(const unsigned short* __restrict__ xp,
                                                const float* __restrict__ offs,
                                                const float* __restrict__ dw_w,
                                                float* __restrict__ out) {
  __shared__ float Cs[8][268];    // padc-padded (256 + 12)
  __shared__ float4 Wt[8][9];     // bilinear weights per (pixel, tap)
  __shared__ int4   Ad[8][9];     // corner row byte-offsets per (pixel, tap)
  __shared__ float  dvs[9][268];  // dw_w transposed [tap][ch], padc-padded

  // XCD-aligned decode: g -> (e, b, m2); chunk c = e*144 + m2 (8 px each)
  int g   = blockIdx.x;          // 0..2303
  int e   = g & 7;
  int idx = g >> 3;              // 0..287
  int b   = idx / 144;
  int m2  = idx - b * 144;       // 0..143
  int c   = e * 144 + m2;        // 0..1151
  int hw0 = c * 8;               // pixel within batch
  int pix0 = b * HWP + hw0;      // global pixel

  int wave = threadIdx.x >> 6;
  int lane = threadIdx.x & 63;
  int hp   = lane >> 5;          // half-wave pixel select (0/1)
  int hl   = lane & 31;          // lane within half-wave
  int ip   = wave * 2 + hp;      // this lane's pixel 0..7
  int c0   = hl * 8;             // this lane's 8-channel base
  int pc0  = padc(c0);           // padded LDS index (16B-aligned)

  const unsigned short* xb = xp + (size_t)b * HWP * CC;
  const float* opb = offs + (size_t)pix0 * 20;

  // ---- phase 0a: stage dw_w transposed (9 scalar loads/thread)
  {
    int t = threadIdx.x;
    int pt = padc(t);
#pragma unroll
    for (int kk = 0; kk < 9; ++kk)
      dvs[kk][pt] = dw_w[t * 9 + kk];
  }

  // ---- phase 0b: 72 threads compute the wave-uniform per-(pixel,tap) data
  {
    int tp = threadIdx.x;
    if (tp < 72) {
      int ipp = tp / 9;              // pixel 0..7
      int kk = tp - ipp * 9;         // tap 0..8
      int hw = hw0 + ipp;
      int h = hw / WW;
      int wq = hw - h * WW;
      float2 o2 = *(const float2*)(opb + ipp * 20 + 2 * kk);
      float y = (float)(h + kk / 3 - 1) + o2.x;
      float x = (float)(wq + kk % 3 - 1) + o2.y;
      float y0f = floorf(y), x0f = floorf(x);
      float fy = y - y0f, fx = x - x0f;
      int y0 = (int)y0f, x0 = (int)x0f;
      int y1 = y0 + 1, x1 = x0 + 1;
      bool vy0 = (y0 >= 0) & (y0 < HH);
      bool vy1 = (y1 >= 0) & (y1 < HH);
      bool vx0 = (x0 >= 0) & (x0 < WW);
      bool vx1 = (x1 >= 0) & (x1 < WW);
      int y0c = y0 < 0 ? 0 : (y0 > HH - 1 ? HH - 1 : y0);
      int y1c = y1 < 0 ? 0 : (y1 > HH - 1 ? HH - 1 : y1);
      int x0c = x0 < 0 ? 0 : (x0 > WW - 1 ? WW - 1 : x0);
      int x1c = x1 < 0 ? 0 : (x1 > WW - 1 ? WW - 1 : x1);
      Wt[ipp][kk] = make_float4(
          (1.f - fy) * (1.f - fx) * ((vy0 && vx0) ? 1.f : 0.f),
          (1.f - fy) * fx         * ((vy0 && vx1) ? 1.f : 0.f),
          fy * (1.f - fx)         * ((vy1 && vx0) ? 1.f : 0.f),
          fy * fx                 * ((vy1 && vx1) ? 1.f : 0.f));
      Ad[ipp][kk] = make_int4((y0c * WW + x0c) * (CC * 2), (y0c * WW + x1c) * (CC * 2),
                              (y1c * WW + x0c) * (CC * 2), (y1c * WW + x1c) * (CC * 2));
    }
  }
  __syncthreads();

  // ---- main loop: 4 uint4 corner loads per tap; unpack + FMA only.
  const char* xbc = (const char*)xb;
  unsigned lb = (unsigned)(hl * 16);   // this lane's 8-channel byte offset

  float acc[8] = {};
#pragma unroll
  for (int kk = 0; kk < 9; ++kk) {
    float4 dv0 = *(const float4*)&dvs[kk][pc0];
    float4 dv1 = *(const float4*)&dvs[kk][pc0 + 4];
    float4 wv = Wt[ip][kk];
    int4 av = Ad[ip][kk];
    uint4 u00 = *(const uint4*)(xbc + ((unsigned)av.x + lb));
    uint4 u01 = *(const uint4*)(xbc + ((unsigned)av.y + lb));
    uint4 u10 = *(const uint4*)(xbc + ((unsigned)av.z + lb));
    uint4 u11 = *(const uint4*)(xbc + ((unsigned)av.w + lb));
    const unsigned* p00 = (const unsigned*)&u00;
    const unsigned* p01 = (const unsigned*)&u01;
    const unsigned* p10 = (const unsigned*)&u10;
    const unsigned* p11 = (const unsigned*)&u11;
    float dvv[8] = {dv0.x, dv0.y, dv0.z, dv0.w, dv1.x, dv1.y, dv1.z, dv1.w};
#pragma unroll
    for (int j = 0; j < 4; ++j) {
      unsigned w00 = p00[j], w01 = p01[j], w10 = p10[j], w11 = p11[j];
      float slo = wv.x * bf_lo(w00) + wv.y * bf_lo(w01) + wv.z * bf_lo(w10) + wv.w * bf_lo(w11);
      float shi = wv.x * bf_hi(w00) + wv.y * bf_hi(w01) + wv.z * bf_hi(w10) + wv.w * bf_hi(w11);
      acc[2 * j]     += dvv[2 * j]     * slo;
      acc[2 * j + 1] += dvv[2 * j + 1] * shi;
    }
  }
  *(float4*)&Cs[ip][pc0]     = make_float4(acc[0], acc[1], acc[2], acc[3]);
  *(float4*)&Cs[ip][pc0 + 4] = make_float4(acc[4], acc[5], acc[6], acc[7]);
  __syncthreads();
  // write-out: thread t = channel, 8 consecutive pixels = 32 B contiguous.
  int ch = threadIdx.x;
  int pch = padc(ch);
  float* ob = out + (size_t)b * CC * HWP + (size_t)ch * HWP + hw0;
  *(float4*)(ob + 0) = make_float4(Cs[0][pch], Cs[1][pch], Cs[2][pch], Cs[3][pch]);
  *(float4*)(ob + 4) = make_float4(Cs[4][pch], Cs[5][pch], Cs[6][pch], Cs[7][pch]);
}

extern "C" void kernel_launch(void* const* d_in, const int* in_sizes, int n_in,
                              void* d_out, int out_size, void* d_ws, size_t ws_size,
                              hipStream_t stream) {
  (void)in_sizes; (void)n_in; (void)out_size; (void)ws_size;
  const float* x     = (const float*)d_in[0];
  const float* pw_w  = (const float*)d_in[1];
  const float* off_w = (const float*)d_in[2];
  const float* off_b = (const float*)d_in[3];
  const float* dw_w  = (const float*)d_in[4];
  float* out = (float*)d_out;

  char* ws = (char*)d_ws;
  unsigned short* xpb = (unsigned short*)ws;            // B*HW*C bf16 = 9,437,184 B
  float* offs = (float*)(ws + 9437184);                 // B*HW*20 f32 = 1,474,560 B

  k_main  <<<576, 256, 0, stream>>>(x, pw_w, off_w, off_b, xpb, offs);
  k_gather<<<2304, 256, 0, stream>>>(xpb, offs, dw_w, out);
}

// Round 11
// 113.167 us; speedup vs baseline: 1.3482x; 1.0252x over previous
//
#include <hip/hip_runtime.h>
#include <hip/hip_bf16.h>

#define HWP 9216   // H*W
#define HH  96
#define WW  96
#define CC  256    // Cin == Cout
#define NB  2

typedef __attribute__((ext_vector_type(8))) short bf16x8;
typedef __attribute__((ext_vector_type(4))) float f32x4;

__device__ inline unsigned short f2bf(float f) {
  union { __hip_bfloat16 h; unsigned short u; } cvt;
  cvt.h = __float2bfloat16(f);
  return cvt.u;
}
__device__ inline float bf_lo(unsigned int u) { return __uint_as_float(u << 16); }
__device__ inline float bf_hi(unsigned int u) { return __uint_as_float(u & 0xffff0000u); }
// LDS anti-bank-conflict padding (R18): +4 floats every 64 -> 2-way (free).
__device__ inline int padc(int c) { return c + ((c >> 6) << 2); }

// ====================== R20 == R19 resubmitted ======================
// R10 bench was an INFRA failure (container failed twice) — no kernel signal;
// resubmitting byte-identical R19 for a clean single-variable measurement.
// Accounting (R17-anchored): fixed fills/overhead ~70us, k_main ~13us,
// k_gather ~33us. R18 (padc) = +0.9us: conflicts were off the critical path
// (gather is latency-bound, VALU ~20%).
// R19 = reinstate R17's VERIFIED BN-split k_main (grid 1152, LDS 25.6KB,
// ~4.5 blk/CU, acc 4 regs) — the R17 regression was entirely k_gather's 0o
// phase (74.2us visible), not this. Offs-epilogue blocker solved WITHOUT
// atomics/recompute: each half-block writes a PARTIAL offs dot (its K=128
// slice, 4 K-steps) to offs0/offs1; k_gather phase 0b sums them (2 float2
// loads, 72 threads, once/block). f32 associativity change only (~1e-6).
// PITFALLS: R12 cooperative grid.sync broken under graph capture; R17 no
// per-block offs recompute; R6/R7 no MFMA-frag reg-prefetch; R9 no BK=64;
// R6 no launch-bounds min-wave; R4 no nontemporal out stores; R8 no VGPR
// blowup in gather.

__global__ __launch_bounds__(256) void k_main(const float* __restrict__ x,
                                              const float* __restrict__ pw_w,
                                              const float* __restrict__ off_w,
                                              const float* __restrict__ off_b,
                                              unsigned short* __restrict__ xpb,
                                              float* __restrict__ offs0,
                                              float* __restrict__ offs1) {
  __shared__ unsigned short As[2][32 * 40];    // [pix][k] dbuf
  __shared__ unsigned short Bs[2][128 * 40];   // [n][k] dbuf; Bs[0] reused as Cs

  // XCD-aligned decode: g -> (e, nh, b, m); both ch-halves of a strip share e
  int g    = blockIdx.x;         // 0..1151
  int e    = g & 7;
  int idx  = g >> 3;             // 0..143
  int nh   = idx & 1;            // channel half
  int idx2 = idx >> 1;           // 0..71
  int b    = idx2 / 36;
  int m    = idx2 - b * 36;      // 0..35
  int pix0 = (e * 36 + m) * 32;  // local pixel within batch
  int nb0  = nh * 128;           // output-channel base

  int t    = threadIdx.x;
  int lane = t & 63;
  int w    = t >> 6;
  int mw  = (w & 1) * 16;        // wave pixel tile
  int nwl = (w >> 1) * 64;       // wave channel quarter (of 128)
  int r = lane & 15, q = lane >> 4;

  f32x4 acc[4] = {};

  const float* xg = x + (size_t)b * CC * HWP + pix0;
  int sc = t >> 3;           // channel within 32-chunk
  int sp = (t & 7) * 4;      // pixel offset
  int nB = t >> 1;           // B row (0..127)
  int kh = (t & 1) * 16;     // B k-offset

  // ---- prologue: stage K-step 0 into buf 0 (B converted inline from f32)
  {
    f32x4 xv = *(const f32x4*)(xg + (size_t)sc * HWP + sp);
    As[0][(sp + 0) * 40 + sc] = f2bf(xv.x);
    As[0][(sp + 1) * 40 + sc] = f2bf(xv.y);
    As[0][(sp + 2) * 40 + sc] = f2bf(xv.z);
    As[0][(sp + 3) * 40 + sc] = f2bf(xv.w);
    const float* wp = pw_w + (size_t)(nb0 + nB) * 256 + kh;
#pragma unroll
    for (int h = 0; h < 2; ++h) {
      float4 w0 = *(const float4*)(wp + h * 8);
      float4 w1 = *(const float4*)(wp + h * 8 + 4);
      union { ushort4 s[2]; uint4 q4; } pk;
      pk.s[0] = make_ushort4(f2bf(w0.x), f2bf(w0.y), f2bf(w0.z), f2bf(w0.w));
      pk.s[1] = make_ushort4(f2bf(w1.x), f2bf(w1.y), f2bf(w1.z), f2bf(w1.w));
      *(uint4*)&Bs[0][nB * 40 + kh + h * 8] = pk.q4;
    }
  }
  __syncthreads();

  // ---- main loop: 1 barrier per K-step, prefetch t+1 overlapped with MFMA(t)
  for (int kt = 0; kt < 8; ++kt) {
    int cur = kt & 1;
    f32x4 xv;
    float4 b0[2], b1[2];
    bool pre = (kt < 7);
    if (pre) {
      int k0 = (kt + 1) * 32;
      xv = *(const f32x4*)(xg + (size_t)(k0 + sc) * HWP + sp);
      const float* wp = pw_w + (size_t)(nb0 + nB) * 256 + k0 + kh;
#pragma unroll
      for (int h = 0; h < 2; ++h) {
        b0[h] = *(const float4*)(wp + h * 8);
        b1[h] = *(const float4*)(wp + h * 8 + 4);
      }
    }
    bf16x8 a = *(const bf16x8*)&As[cur][(mw + r) * 40 + q * 8];
#pragma unroll
    for (int nt = 0; nt < 4; ++nt) {
      bf16x8 bb = *(const bf16x8*)&Bs[cur][(nwl + nt * 16 + r) * 40 + q * 8];
      acc[nt] = __builtin_amdgcn_mfma_f32_16x16x32_bf16(a, bb, acc[nt], 0, 0, 0);
    }
    if (pre) {
      int nx = cur ^ 1;
      As[nx][(sp + 0) * 40 + sc] = f2bf(xv.x);
      As[nx][(sp + 1) * 40 + sc] = f2bf(xv.y);
      As[nx][(sp + 2) * 40 + sc] = f2bf(xv.z);
      As[nx][(sp + 3) * 40 + sc] = f2bf(xv.w);
#pragma unroll
      for (int h = 0; h < 2; ++h) {
        union { ushort4 s[2]; uint4 q4; } pk;
        pk.s[0] = make_ushort4(f2bf(b0[h].x), f2bf(b0[h].y), f2bf(b0[h].z), f2bf(b0[h].w));
        pk.s[1] = make_ushort4(f2bf(b1[h].x), f2bf(b1[h].y), f2bf(b1[h].z), f2bf(b1[h].w));
        *(uint4*)&Bs[nx][nB * 40 + kh + h * 8] = pk.q4;
      }
    }
    __syncthreads();
  }

  // Cs aliases Bs[0]: last K-step read buf 1; final sync drained buf 0 reads.
  unsigned short* Cs = &Bs[0][0];   // [32][136] bf16 (4352 shorts <= 5120)

  // C/D: col = lane&15 (ch), row = q*4+rr (pix) -> Cs[pix][ch] bf16
#pragma unroll
  for (int nt = 0; nt < 4; ++nt)
#pragma unroll
    for (int rr = 0; rr < 4; ++rr)
      Cs[(mw + q * 4 + rr) * 136 + nwl + nt * 16 + r] = f2bf(acc[nt][rr]);
  __syncthreads();

  // write xpb coalesced: 32 B contiguous per thread (128-ch half)
  {
    int pix = t >> 3, c16 = (t & 7) * 16;
    unsigned short* o = xpb + ((size_t)b * HWP + pix0 + pix) * CC + nb0 + c16;
    *(uint4*)(o + 0) = *(const uint4*)&Cs[pix * 136 + c16 + 0];
    *(uint4*)(o + 8) = *(const uint4*)&Cs[pix * 136 + c16 + 8];
  }

  // offs PARTIAL epilogue over this block's K=128 slice (4 K-steps):
  // offs_h[pix, o] = sum_{c in half} Cs[pix][c] * off_w[o][nb0+c] (+off_b if nh==0)
  {
    float* offs_h = nh ? offs1 : offs0;
    int mw2 = (w & 1) * 16;    // pixel tile
    int nw2 = (w >> 1) * 16;   // o tile (0 or 16)
    int row = nw2 + r;
    f32x4 oacc = {};
#pragma unroll
    for (int ks = 0; ks < 128; ks += 32) {
      bf16x8 a = *(const bf16x8*)&Cs[(mw2 + r) * 136 + ks + q * 8];
      bf16x8 bb = {};
      if (row < 18) {
        const float* wp = off_w + row * 256 + nb0 + ks + q * 8;
        float4 w0 = *(const float4*)wp;
        float4 w1 = *(const float4*)(wp + 4);
        union { unsigned short u[8]; bf16x8 v; } pk;
        pk.u[0] = f2bf(w0.x); pk.u[1] = f2bf(w0.y); pk.u[2] = f2bf(w0.z); pk.u[3] = f2bf(w0.w);
        pk.u[4] = f2bf(w1.x); pk.u[5] = f2bf(w1.y); pk.u[6] = f2bf(w1.z); pk.u[7] = f2bf(w1.w);
        bb = pk.v;
      }
      oacc = __builtin_amdgcn_mfma_f32_16x16x32_bf16(a, bb, oacc, 0, 0, 0);
    }
    if (row < 18) {
      float ob = nh ? 0.f : off_b[row];
      size_t base = ((size_t)b * HWP + pix0 + mw2 + q * 4) * 20 + row;
#pragma unroll
      for (int rr = 0; rr < 4; ++rr)
        offs_h[base + (size_t)rr * 20] = oacc[rr] + ob;
    }
  }
}

// ---- gather + depthwise: R18 exactly (8 px/block, half-wave pixel split,
// uint4 corner loads, padc LDS), except phase 0b sums offs0+offs1.
__global__ __launch_bounds__(256) void k_gather(const unsigned short* __restrict__ xp,
                                                const float* __restrict__ offs0,
                                                const float* __restrict__ offs1,
                                                const float* __restrict__ dw_w,
                                                float* __restrict__ out) {
  __shared__ float Cs[8][268];    // padc-padded (256 + 12)
  __shared__ float4 Wt[8][9];     // bilinear weights per (pixel, tap)
  __shared__ int4   Ad[8][9];     // corner row byte-offsets per (pixel, tap)
  __shared__ float  dvs[9][268];  // dw_w transposed [tap][ch], padc-padded

  // XCD-aligned decode: g -> (e, b, m2); chunk c = e*144 + m2 (8 px each)
  int g   = blockIdx.x;          // 0..2303
  int e   = g & 7;
  int idx = g >> 3;              // 0..287
  int b   = idx / 144;
  int m2  = idx - b * 144;       // 0..143
  int c   = e * 144 + m2;        // 0..1151
  int hw0 = c * 8;               // pixel within batch
  int pix0 = b * HWP + hw0;      // global pixel

  int wave = threadIdx.x >> 6;
  int lane = threadIdx.x & 63;
  int hp   = lane >> 5;          // half-wave pixel select (0/1)
  int hl   = lane & 31;          // lane within half-wave
  int ip   = wave * 2 + hp;      // this lane's pixel 0..7
  int c0   = hl * 8;             // this lane's 8-channel base
  int pc0  = padc(c0);           // padded LDS index (16B-aligned)

  const unsigned short* xb = xp + (size_t)b * HWP * CC;
  const float* opb0 = offs0 + (size_t)pix0 * 20;
  const float* opb1 = offs1 + (size_t)pix0 * 20;

  // ---- phase 0a: stage dw_w transposed (9 scalar loads/thread)
  {
    int t = threadIdx.x;
    int pt = padc(t);
#pragma unroll
    for (int kk = 0; kk < 9; ++kk)
      dvs[kk][pt] = dw_w[t * 9 + kk];
  }

  // ---- phase 0b: 72 threads compute the wave-uniform per-(pixel,tap) data
  {
    int tp = threadIdx.x;
    if (tp < 72) {
      int ipp = tp / 9;              // pixel 0..7
      int kk = tp - ipp * 9;         // tap 0..8
      int hw = hw0 + ipp;
      int h = hw / WW;
      int wq = hw - h * WW;
      float2 oa = *(const float2*)(opb0 + ipp * 20 + 2 * kk);
      float2 ob = *(const float2*)(opb1 + ipp * 20 + 2 * kk);
      float y = (float)(h + kk / 3 - 1) + oa.x + ob.x;
      float x = (float)(wq + kk % 3 - 1) + oa.y + ob.y;
      float y0f = floorf(y), x0f = floorf(x);
      float fy = y - y0f, fx = x - x0f;
      int y0 = (int)y0f, x0 = (int)x0f;
      int y1 = y0 + 1, x1 = x0 + 1;
      bool vy0 = (y0 >= 0) & (y0 < HH);
      bool vy1 = (y1 >= 0) & (y1 < HH);
      bool vx0 = (x0 >= 0) & (x0 < WW);
      bool vx1 = (x1 >= 0) & (x1 < WW);
      int y0c = y0 < 0 ? 0 : (y0 > HH - 1 ? HH - 1 : y0);
      int y1c = y1 < 0 ? 0 : (y1 > HH - 1 ? HH - 1 : y1);
      int x0c = x0 < 0 ? 0 : (x0 > WW - 1 ? WW - 1 : x0);
      int x1c = x1 < 0 ? 0 : (x1 > WW - 1 ? WW - 1 : x1);
      Wt[ipp][kk] = make_float4(
          (1.f - fy) * (1.f - fx) * ((vy0 && vx0) ? 1.f : 0.f),
          (1.f - fy) * fx         * ((vy0 && vx1) ? 1.f : 0.f),
          fy * (1.f - fx)         * ((vy1 && vx0) ? 1.f : 0.f),
          fy * fx                 * ((vy1 && vx1) ? 1.f : 0.f));
      Ad[ipp][kk] = make_int4((y0c * WW + x0c) * (CC * 2), (y0c * WW + x1c) * (CC * 2),
                              (y1c * WW + x0c) * (CC * 2), (y1c * WW + x1c) * (CC * 2));
    }
  }
  __syncthreads();

  // ---- main loop: 4 uint4 corner loads per tap; unpack + FMA only.
  const char* xbc = (const char*)xb;
  unsigned lb = (unsigned)(hl * 16);   // this lane's 8-channel byte offset

  float acc[8] = {};
#pragma unroll
  for (int kk = 0; kk < 9; ++kk) {
    float4 dv0 = *(const float4*)&dvs[kk][pc0];
    float4 dv1 = *(const float4*)&dvs[kk][pc0 + 4];
    float4 wv = Wt[ip][kk];
    int4 av = Ad[ip][kk];
    uint4 u00 = *(const uint4*)(xbc + ((unsigned)av.x + lb));
    uint4 u01 = *(const uint4*)(xbc + ((unsigned)av.y + lb));
    uint4 u10 = *(const uint4*)(xbc + ((unsigned)av.z + lb));
    uint4 u11 = *(const uint4*)(xbc + ((unsigned)av.w + lb));
    const unsigned* p00 = (const unsigned*)&u00;
    const unsigned* p01 = (const unsigned*)&u01;
    const unsigned* p10 = (const unsigned*)&u10;
    const unsigned* p11 = (const unsigned*)&u11;
    float dvv[8] = {dv0.x, dv0.y, dv0.z, dv0.w, dv1.x, dv1.y, dv1.z, dv1.w};
#pragma unroll
    for (int j = 0; j < 4; ++j) {
      unsigned w00 = p00[j], w01 = p01[j], w10 = p10[j], w11 = p11[j];
      float slo = wv.x * bf_lo(w00) + wv.y * bf_lo(w01) + wv.z * bf_lo(w10) + wv.w * bf_lo(w11);
      float shi = wv.x * bf_hi(w00) + wv.y * bf_hi(w01) + wv.z * bf_hi(w10) + wv.w * bf_hi(w11);
      acc[2 * j]     += dvv[2 * j]     * slo;
      acc[2 * j + 1] += dvv[2 * j + 1] * shi;
    }
  }
  *(float4*)&Cs[ip][pc0]     = make_float4(acc[0], acc[1], acc[2], acc[3]);
  *(float4*)&Cs[ip][pc0 + 4] = make_float4(acc[4], acc[5], acc[6], acc[7]);
  __syncthreads();
  // write-out: thread t = channel, 8 consecutive pixels = 32 B contiguous.
  int ch = threadIdx.x;
  int pch = padc(ch);
  float* ob = out + (size_t)b * CC * HWP + (size_t)ch * HWP + hw0;
  *(float4*)(ob + 0) = make_float4(Cs[0][pch], Cs[1][pch], Cs[2][pch], Cs[3][pch]);
  *(float4*)(ob + 4) = make_float4(Cs[4][pch], Cs[5][pch], Cs[6][pch], Cs[7][pch]);
}

extern "C" void kernel_launch(void* const* d_in, const int* in_sizes, int n_in,
                              void* d_out, int out_size, void* d_ws, size_t ws_size,
                              hipStream_t stream) {
  (void)in_sizes; (void)n_in; (void)out_size; (void)ws_size;
  const float* x     = (const float*)d_in[0];
  const float* pw_w  = (const float*)d_in[1];
  const float* off_w = (const float*)d_in[2];
  const float* off_b = (const float*)d_in[3];
  const float* dw_w  = (const float*)d_in[4];
  float* out = (float*)d_out;

  char* ws = (char*)d_ws;
  unsigned short* xpb = (unsigned short*)ws;             // B*HW*C bf16 = 9,437,184 B
  float* offs0 = (float*)(ws + 9437184);                 // B*HW*20 f32 = 1,474,560 B
  float* offs1 = (float*)(ws + 10911744);                // B*HW*20 f32 = 1,474,560 B

  k_main  <<<1152, 256, 0, stream>>>(x, pw_w, off_w, off_b, xpb, offs0, offs1);
  k_gather<<<2304, 256, 0, stream>>>(xpb, offs0, offs1, dw_w, out);
}